// Round 1
// baseline (451.391 us; speedup 1.0000x reference)
//
#include <hip/hip_runtime.h>

// Problem constants
#define S_LEN 2048
#define NH    16
#define HD    64
#define EMB   1024
#define NB    4
#define MROWS (NB * S_LEN)   // 8192

typedef __attribute__((ext_vector_type(8))) short  short8;   // 8 x bf16 bits (4 VGPRs)
typedef __attribute__((ext_vector_type(4))) float  float4_t; // MFMA C/D frag
typedef __attribute__((ext_vector_type(4))) int    int4_t;   // 16B int vector
union U8 { int4_t i; short8 s; };

__device__ __forceinline__ unsigned short f2bf(float f) {
    unsigned int x = __float_as_uint(f);
    unsigned int r = (x + 0x7fffu + ((x >> 16) & 1u)) >> 16;   // RNE
    return (unsigned short)r;
}

typedef const __attribute__((address_space(1))) unsigned int* gas_ptr;
typedef __attribute__((address_space(3))) unsigned int*       las_ptr;
__device__ __forceinline__ void gld_lds16(const void* g, void* l) {
    __builtin_amdgcn_global_load_lds((gas_ptr)g, (las_ptr)l, 16, 0, 0);
}

// ---------------------------------------------------------------------------
// elementwise fp32 -> bf16 (x), 2 elems/thread
// ---------------------------------------------------------------------------
__global__ void cvt_f32_bf16(const float* __restrict__ in,
                             unsigned short* __restrict__ out, int n2) {
    int i = blockIdx.x * blockDim.x + threadIdx.x;
    if (i < n2) {
        float2 v = ((const float2*)in)[i];
        ushort2 o; o.x = f2bf(v.x); o.y = f2bf(v.y);
        ((ushort2*)out)[i] = o;
    }
}

// ---------------------------------------------------------------------------
// fp32 transpose + convert: out_bf16[C][R] = in_f32[R][C]
// ---------------------------------------------------------------------------
__global__ void transpose_f32_bf16(const float* __restrict__ in,
                                   unsigned short* __restrict__ out, int R, int C) {
    __shared__ float tile[32][33];
    int n0 = blockIdx.x * 32, r0 = blockIdx.y * 32;
    int tx = threadIdx.x, ty = threadIdx.y;     // (32,8)
#pragma unroll
    for (int i = 0; i < 4; ++i)
        tile[ty + i * 8][tx] = in[(size_t)(r0 + ty + i * 8) * C + n0 + tx];
    __syncthreads();
#pragma unroll
    for (int i = 0; i < 4; ++i)
        out[(size_t)(n0 + ty + i * 8) * R + r0 + tx] = f2bf(tile[tx][ty + i * 8]);
}

// ---------------------------------------------------------------------------
// GEMM1: qkv = Xb[8192,1024] @ WqkvT[3072,1024]^T + bqkv(f32)
// epilogue scatters to Q[B,H,S,D], K[B,H,S,D], VT[B,H,D,S]  (all bf16)
// VT stores merged into 8B/lane (4 consecutive s) to avoid 2B scatter.
// ---------------------------------------------------------------------------
__global__ __launch_bounds__(256) void gemm_qkv(
    const unsigned short* __restrict__ X,
    const unsigned short* __restrict__ WT,
    const float* __restrict__ bias,
    unsigned short* __restrict__ Qb,
    unsigned short* __restrict__ Kb,
    unsigned short* __restrict__ VTb)
{
    __shared__ alignas(16) unsigned short As[128 * 32];
    __shared__ alignas(16) unsigned short Bs[128 * 32];
    const int K = 1024;
    int t = threadIdx.x;
    int wave = t >> 6, lane = t & 63, quad = lane >> 4, l = lane & 15;
    int bm = blockIdx.x * 128, bn = blockIdx.y * 128;
    int wm = (wave >> 1) * 64, wn = (wave & 1) * 64;

    float4_t z = {0.f, 0.f, 0.f, 0.f};
    float4_t acc[4][4];
#pragma unroll
    for (int i = 0; i < 4; ++i)
#pragma unroll
        for (int j = 0; j < 4; ++j) acc[i][j] = z;

    for (int kt = 0; kt < K / 32; ++kt) {
        int k0 = kt * 32;
        if (kt) __syncthreads();
#pragma unroll
        for (int it = 0; it < 2; ++it) {
            int c = t + 256 * it;
            int row = c >> 2, col = (c & 3) * 8;
            gld_lds16(&X [(size_t)(bm + row) * K + k0 + col], &As[c * 8]);
            gld_lds16(&WT[(size_t)(bn + row) * K + k0 + col], &Bs[c * 8]);
        }
        __syncthreads();
        short8 af[4], bfr[4];
#pragma unroll
        for (int i = 0; i < 4; ++i)
            af[i] = *(const short8*)&As[(wm + i * 16 + l) * 32 + quad * 8];
#pragma unroll
        for (int j = 0; j < 4; ++j)
            bfr[j] = *(const short8*)&Bs[(wn + j * 16 + l) * 32 + quad * 8];
#pragma unroll
        for (int i = 0; i < 4; ++i)
#pragma unroll
            for (int j = 0; j < 4; ++j)
                acc[i][j] = __builtin_amdgcn_mfma_f32_16x16x32_bf16(
                    af[i], bfr[j], acc[i][j], 0, 0, 0);
    }
#pragma unroll
    for (int j = 0; j < 4; ++j) {
        int gc = bn + wn + j * 16 + l;
        float bv = bias[gc];
        int which = gc >> 10, rem = gc & 1023;
        int h = rem >> 6, d = rem & 63;
        if (which == 2) {
            int bb = bm >> 11;
            size_t rowbase = ((size_t)(bb * NH + h) * HD + d) * S_LEN;
#pragma unroll
            for (int i = 0; i < 4; ++i) {
                unsigned int u0 = __float_as_uint(acc[i][j][0] + bv) + 0x8000u;
                unsigned int u1 = __float_as_uint(acc[i][j][1] + bv) + 0x8000u;
                unsigned int u2 = __float_as_uint(acc[i][j][2] + bv) + 0x8000u;
                unsigned int u3 = __float_as_uint(acc[i][j][3] + bv) + 0x8000u;
                uint2 vv;
                vv.x = __builtin_amdgcn_perm(u1, u0, 0x07060302u);
                vv.y = __builtin_amdgcn_perm(u3, u2, 0x07060302u);
                int s0 = (bm + wm + i * 16 + quad * 4) & 2047;
                *(uint2*)&VTb[rowbase + s0] = vv;
            }
        } else {
#pragma unroll
            for (int i = 0; i < 4; ++i)
#pragma unroll
                for (int r = 0; r < 4; ++r) {
                    int gr = bm + wm + i * 16 + quad * 4 + r;
                    int b = gr >> 11, s = gr & 2047;
                    unsigned short ov = f2bf(acc[i][j][r] + bv);
                    size_t bh2 = (size_t)(b * NH + h);
                    if (which == 0) Qb[(bh2 * S_LEN + s) * HD + d] = ov;
                    else            Kb[(bh2 * S_LEN + s) * HD + d] = ov;
                }
        }
    }
}

// ---------------------------------------------------------------------------
// Flash attention (causal), barrier-free, transposed-score formulation.
// Wave = 32 queries of chunk pi AND 32 queries of mirror chunk (63-pi),
// sharing one key-fragment stream (load balance + 2x load reuse).
//
// THIS ROUND: register double-buffered K/V tile prefetch with FORCED batched
// issue.  Previous version let the compiler sink the 24 per-tile global loads
// to right before each use (VGPR_Count=120 < live-set 160 proves it), which
// serialized ~24 x ~300cy L2 latencies per kt-iteration (~7800 cy/iter
// measured vs ~600 cy of compute).  Now: statically-named A/B buffers
// (rule #20: no runtime-indexed reg arrays), loads for tile kt+1 issued
// as one batch before tile kt's compute, sched_barrier(0) fences so the
// scheduler's reg-pressure heuristic cannot re-sink them.  Occupancy is
// grid-capped at 2 waves/SIMD so VGPR budget is 256 - higher VGPR is free.
// ---------------------------------------------------------------------------
__global__ __launch_bounds__(256, 2) void flash_attn(
    const unsigned short* __restrict__ Qb,
    const unsigned short* __restrict__ Kb,
    const unsigned short* __restrict__ VTb,
    unsigned short* __restrict__ AO)
{
    __shared__ alignas(16) unsigned short stg[4][16 * 68];  // per-wave O staging

    int t = threadIdx.x, wave = t >> 6, lane = t & 63, quad = lane >> 4, cl = lane & 15;
    int blk = blockIdx.x;
    int g = blk >> 3;
    int bh = (blk & 7) + 8 * (g & 7);    // XCD-pinned heads
    int pi = (g >> 3) * 4 + wave;        // 0..31 pair index
    int b = bh >> 4, h = bh & 15;
    int qbA = 32 * pi, qbB = 32 * (63 - pi);
    int nktA = ((qbA + 31) >> 6) + 1, nktB = ((qbB + 31) >> 6) + 1;

    const unsigned short* Qbase = Qb  + (size_t)bh * S_LEN * HD;
    const unsigned short* Kbase = Kb  + (size_t)bh * S_LEN * HD;
    const unsigned short* Vbase = VTb + (size_t)bh * HD * S_LEN;

    float4_t z = {0.f, 0.f, 0.f, 0.f};
    short8 bQA[2][2], bQB[2][2];
#pragma unroll
    for (int qt = 0; qt < 2; ++qt)
#pragma unroll
        for (int hh = 0; hh < 2; ++hh) {
            bQA[qt][hh] = *(const short8*)&Qbase[(size_t)(qbA + qt * 16 + cl) * HD + hh * 32 + quad * 8];
            bQB[qt][hh] = *(const short8*)&Qbase[(size_t)(qbB + qt * 16 + cl) * HD + hh * 32 + quad * 8];
        }

    float4_t accA[2][4], accB[2][4];
#pragma unroll
    for (int qt = 0; qt < 2; ++qt)
#pragma unroll
        for (int nb = 0; nb < 4; ++nb) { accA[qt][nb] = z; accB[qt][nb] = z; }
    float psA[2] = {0.f, 0.f}, psB[2] = {0.f, 0.f};

    // double-buffered K/V fragment registers (statically named, never
    // runtime-indexed -> stays in VGPRs)
    short8 aK0a[4], aK1a[4], aK0b[4], aK1b[4];
    uint2 bvloa[2][4], bvhia[2][4], bvlob[2][4], bvhib[2][4];

    auto load_tile = [&](int kt, short8 (&aK0)[4], short8 (&aK1)[4],
                         uint2 (&bvlo)[2][4], uint2 (&bvhi)[2][4]) {
        int key0 = kt << 6;
        // K A-fragments: A[m=key][k=d]  (16B/lane, contiguous)
#pragma unroll
        for (int t4 = 0; t4 < 4; ++t4) {
            const unsigned short* kr = &Kbase[(size_t)(key0 + t4 * 16 + cl) * HD + quad * 8];
            aK0[t4] = *(const short8*)kr;
            aK1[t4] = *(const short8*)(kr + 32);
        }
        // V B-fragments: slots j<4 = keys quad*4..+3, j>=4 = +16 (8B pieces)
#pragma unroll
        for (int p = 0; p < 2; ++p)
#pragma unroll
            for (int nb = 0; nb < 4; ++nb) {
                const unsigned short* vr = &Vbase[(size_t)(nb * 16 + cl) * S_LEN + key0 + p * 32 + quad * 4];
                bvlo[p][nb] = *(const uint2*)vr;
                bvhi[p][nb] = *(const uint2*)(vr + 16);
            }
    };

    auto proc = [&](int kt, int qb, int nkt, short8 (&bQ)[2][2],
                    float4_t (&acc)[2][4], float (&ps)[2],
                    short8 (&aK0)[4], short8 (&aK1)[4],
                    uint2 (&bvlo)[2][4], uint2 (&bvhi)[2][4]) {
        if (kt >= nkt) return;
        int key0 = kt << 6;
        bool diag = (kt == nkt - 1);
#pragma unroll
        for (int qt = 0; qt < 2; ++qt) {
            unsigned int pk[4][2];
#pragma unroll
            for (int t4 = 0; t4 < 4; ++t4) {
                float4_t st = __builtin_amdgcn_mfma_f32_16x16x32_bf16(
                    aK1[t4], bQ[qt][1],
                    __builtin_amdgcn_mfma_f32_16x16x32_bf16(aK0[t4], bQ[qt][0], z, 0, 0, 0),
                    0, 0, 0);
                unsigned int u[4];
#pragma unroll
                for (int r = 0; r < 4; ++r) {
                    float e = __expf(st[r] * 0.125f);      // 1/sqrt(64)
                    if (diag) {
                        int key = key0 + t4 * 16 + quad * 4 + r;
                        e = (key <= qb + qt * 16 + cl) ? e : 0.f;
                    }
                    ps[qt] += e;
                    u[r] = __float_as_uint(e) + 0x8000u;    // round-to-bf16 bias
                }
                pk[t4][0] = __builtin_amdgcn_perm(u[1], u[0], 0x07060302u);
                pk[t4][1] = __builtin_amdgcn_perm(u[3], u[2], 0x07060302u);
            }
#pragma unroll
            for (int p = 0; p < 2; ++p) {
                U8 a; a.i = (int4_t){(int)pk[2 * p][0], (int)pk[2 * p][1],
                                     (int)pk[2 * p + 1][0], (int)pk[2 * p + 1][1]};
#pragma unroll
                for (int nb = 0; nb < 4; ++nb) {
                    U8 bb; bb.i = (int4_t){(int)bvlo[p][nb].x, (int)bvlo[p][nb].y,
                                           (int)bvhi[p][nb].x, (int)bvhi[p][nb].y};
                    acc[qt][nb] = __builtin_amdgcn_mfma_f32_16x16x32_bf16(
                        a.s, bb.s, acc[qt][nb], 0, 0, 0);
                }
            }
        }
    };

    int last = nktB - 1;
    // prologue: tile 0 into A-buffers
    load_tile(0, aK0a, aK1a, bvloa, bvhia);
    for (int kt = 0; kt < nktB; kt += 2) {
        // issue next tile's 24 loads as one batch into B-buffers
        int kt1 = (kt + 1 < last) ? (kt + 1) : last;   // clamped (redundant at tail, harmless)
        load_tile(kt1, aK0b, aK1b, bvlob, bvhib);
        __builtin_amdgcn_sched_barrier(0);             // don't sink loads into compute
        proc(kt, qbA, nktA, bQA, accA, psA, aK0a, aK1a, bvloa, bvhia);
        proc(kt, qbB, nktB, bQB, accB, psB, aK0a, aK1a, bvloa, bvhia);
        // refill A-buffers for kt+2 while computing kt+1 from B-buffers
        int kt2 = (kt + 2 < last) ? (kt + 2) : last;
        load_tile(kt2, aK0a, aK1a, bvloa, bvhia);
        __builtin_amdgcn_sched_barrier(0);
        if (kt + 1 < nktB) {
            proc(kt + 1, qbA, nktA, bQA, accA, psA, aK0b, aK1b, bvlob, bvhib);
            proc(kt + 1, qbB, nktB, bQB, accB, psB, aK0b, aK1b, bvlob, bvhib);
        }
    }

    auto flush = [&](int qb, float4_t (&acc)[2][4], float (&ps)[2]) {
#pragma unroll
        for (int qt = 0; qt < 2; ++qt) {
            float s = ps[qt];
            s += __shfl_xor(s, 16);
            s += __shfl_xor(s, 32);
            float inv = 1.f / s;                 // full sum for query qb+qt*16+cl
            float fr[4];
#pragma unroll
            for (int r = 0; r < 4; ++r) fr[r] = __shfl(inv, quad * 4 + r);
#pragma unroll
            for (int nb = 0; nb < 4; ++nb)
#pragma unroll
                for (int r = 0; r < 4; ++r) {
                    unsigned int u = __float_as_uint(acc[qt][nb][r] * fr[r]) + 0x8000u;
                    stg[wave][(quad * 4 + r) * 68 + nb * 16 + cl] = (unsigned short)(u >> 16);
                }
#pragma unroll
            for (int pass = 0; pass < 4; ++pass) {
                int idx = pass * 64 + lane;
                int row = idx >> 4, part = idx & 15;
                ushort4 v = *(const ushort4*)&stg[wave][row * 68 + part * 4];
                *(ushort4*)&AO[((size_t)b * S_LEN + qb + qt * 16 + row) * EMB + h * HD + part * 4] = v;
            }
        }
    };
    flush(qbA, accA, psA);
    flush(qbB, accB, psB);
}

// ---------------------------------------------------------------------------
// GEMM2: out_f32 = AO[8192,1024]bf16 @ WoutT[1024,1024]^T + bout(f32)
// ---------------------------------------------------------------------------
__global__ __launch_bounds__(256) void gemm_out(
    const unsigned short* __restrict__ A,
    const unsigned short* __restrict__ WT,
    const float* __restrict__ bias,
    float* __restrict__ out)
{
    __shared__ alignas(16) unsigned short As[128 * 32];
    __shared__ alignas(16) unsigned short Bs[128 * 32];
    const int K = 1024;
    int t = threadIdx.x;
    int wave = t >> 6, lane = t & 63, quad = lane >> 4, l = lane & 15;
    int bm = blockIdx.x * 128, bn = blockIdx.y * 128;
    int wm = (wave >> 1) * 64, wn = (wave & 1) * 64;

    float4_t z = {0.f, 0.f, 0.f, 0.f};
    float4_t acc[4][4];
#pragma unroll
    for (int i = 0; i < 4; ++i)
#pragma unroll
        for (int j = 0; j < 4; ++j) acc[i][j] = z;

    for (int kt = 0; kt < K / 32; ++kt) {
        int k0 = kt * 32;
        if (kt) __syncthreads();
#pragma unroll
        for (int it = 0; it < 2; ++it) {
            int c = t + 256 * it;
            int row = c >> 2, col = (c & 3) * 8;
            gld_lds16(&A [(size_t)(bm + row) * K + k0 + col], &As[c * 8]);
            gld_lds16(&WT[(size_t)(bn + row) * K + k0 + col], &Bs[c * 8]);
        }
        __syncthreads();
        short8 af[4], bfr[4];
#pragma unroll
        for (int i = 0; i < 4; ++i)
            af[i] = *(const short8*)&As[(wm + i * 16 + l) * 32 + quad * 8];
#pragma unroll
        for (int j = 0; j < 4; ++j)
            bfr[j] = *(const short8*)&Bs[(wn + j * 16 + l) * 32 + quad * 8];
#pragma unroll
        for (int i = 0; i < 4; ++i)
#pragma unroll
            for (int j = 0; j < 4; ++j)
                acc[i][j] = __builtin_amdgcn_mfma_f32_16x16x32_bf16(
                    af[i], bfr[j], acc[i][j], 0, 0, 0);
    }
#pragma unroll
    for (int j = 0; j < 4; ++j) {
        int gc = bn + wn + j * 16 + l;
        float bv = bias[gc];
#pragma unroll
        for (int i = 0; i < 4; ++i) {
#pragma unroll
            for (int r = 0; r < 4; ++r) {
                int gr = bm + wm + i * 16 + quad * 4 + r;
                out[(size_t)gr * EMB + gc] = acc[i][j][r] + bv;
            }
        }
    }
}

// ---------------------------------------------------------------------------
extern "C" void kernel_launch(void* const* d_in, const int* in_sizes, int n_in,
                              void* d_out, int out_size, void* d_ws, size_t ws_size,
                              hipStream_t stream) {
    const float* x    = (const float*)d_in[0];
    // d_in[1] = causal mask (int32 tril) -- implemented analytically, not read
    const float* Wqkv = (const float*)d_in[2];
    const float* bqkv = (const float*)d_in[3];
    const float* Wout = (const float*)d_in[4];
    const float* bout = (const float*)d_in[5];
    float* out = (float*)d_out;

    // workspace (bf16): Q 16MB | K 16MB | VT 16MB | Xb/AO 16MB (aliased) |
    // WqkvT 6MB | WoutT 2MB = 72MB
    char* ws = (char*)d_ws;
    const size_t SZ = (size_t)NB * NH * S_LEN * HD * 2;  // 16 MiB
    unsigned short* Qb    = (unsigned short*)(ws);
    unsigned short* Kb    = (unsigned short*)(ws + SZ);
    unsigned short* VTb   = (unsigned short*)(ws + 2 * SZ);
    unsigned short* Xb    = (unsigned short*)(ws + 3 * SZ);
    unsigned short* AO    = (unsigned short*)(ws + 3 * SZ);  // alias with Xb
    unsigned short* WqkvT = (unsigned short*)(ws + 4 * SZ);
    unsigned short* WoutT = (unsigned short*)(ws + 4 * SZ + (size_t)3 * EMB * EMB * 2);

    int n2 = MROWS * EMB / 2;
    cvt_f32_bf16<<<dim3((n2 + 255) / 256), 256, 0, stream>>>(x, Xb, n2);
    dim3 tb(32, 8);
    transpose_f32_bf16<<<dim3(3 * EMB / 32, EMB / 32), tb, 0, stream>>>(Wqkv, WqkvT, EMB, 3 * EMB);
    transpose_f32_bf16<<<dim3(EMB / 32, EMB / 32), tb, 0, stream>>>(Wout, WoutT, EMB, EMB);
    gemm_qkv<<<dim3(MROWS / 128, 3 * EMB / 128), 256, 0, stream>>>(Xb, WqkvT, bqkv, Qb, Kb, VTb);
    flash_attn<<<dim3(512), 256, 0, stream>>>(Qb, Kb, VTb, AO);
    gemm_out<<<dim3(MROWS / 128, EMB / 128), 256, 0, stream>>>(AO, WoutT, bout, out);
}

// Round 2
// 411.242 us; speedup vs baseline: 1.0976x; 1.0976x over previous
//
#include <hip/hip_runtime.h>

// Problem constants
#define S_LEN 2048
#define NH    16
#define HD    64
#define EMB   1024
#define NB    4
#define MROWS (NB * S_LEN)   // 8192

typedef __attribute__((ext_vector_type(8))) short  short8;   // 8 x bf16 bits (4 VGPRs)
typedef __attribute__((ext_vector_type(4))) float  float4_t; // MFMA C/D frag
typedef __attribute__((ext_vector_type(4))) int    int4_t;   // 16B int vector
union U8 { int4_t i; short8 s; };

__device__ __forceinline__ unsigned short f2bf(float f) {
    unsigned int x = __float_as_uint(f);
    unsigned int r = (x + 0x7fffu + ((x >> 16) & 1u)) >> 16;   // RNE
    return (unsigned short)r;
}

typedef const __attribute__((address_space(1))) unsigned int* gas_ptr;
typedef __attribute__((address_space(3))) unsigned int*       las_ptr;
__device__ __forceinline__ void gld_lds16(const void* g, void* l) {
    __builtin_amdgcn_global_load_lds((gas_ptr)g, (las_ptr)l, 16, 0, 0);
}

// ---------------------------------------------------------------------------
// elementwise fp32 -> bf16 (x), 2 elems/thread
// ---------------------------------------------------------------------------
__global__ void cvt_f32_bf16(const float* __restrict__ in,
                             unsigned short* __restrict__ out, int n2) {
    int i = blockIdx.x * blockDim.x + threadIdx.x;
    if (i < n2) {
        float2 v = ((const float2*)in)[i];
        ushort2 o; o.x = f2bf(v.x); o.y = f2bf(v.y);
        ((ushort2*)out)[i] = o;
    }
}

// ---------------------------------------------------------------------------
// fp32 transpose + convert: out_bf16[C][R] = in_f32[R][C]
// ---------------------------------------------------------------------------
__global__ void transpose_f32_bf16(const float* __restrict__ in,
                                   unsigned short* __restrict__ out, int R, int C) {
    __shared__ float tile[32][33];
    int n0 = blockIdx.x * 32, r0 = blockIdx.y * 32;
    int tx = threadIdx.x, ty = threadIdx.y;     // (32,8)
#pragma unroll
    for (int i = 0; i < 4; ++i)
        tile[ty + i * 8][tx] = in[(size_t)(r0 + ty + i * 8) * C + n0 + tx];
    __syncthreads();
#pragma unroll
    for (int i = 0; i < 4; ++i)
        out[(size_t)(n0 + ty + i * 8) * R + r0 + tx] = f2bf(tile[tx][ty + i * 8]);
}

// ---------------------------------------------------------------------------
// GEMM1: qkv = Xb[8192,1024] @ WqkvT[3072,1024]^T + bqkv(f32)
// epilogue scatters to Q[B,H,S,D], K[B,H,S,D], VT[B,H,D,S]  (all bf16)
// VT stores merged into 8B/lane (4 consecutive s) to avoid 2B scatter.
// ---------------------------------------------------------------------------
__global__ __launch_bounds__(256) void gemm_qkv(
    const unsigned short* __restrict__ X,
    const unsigned short* __restrict__ WT,
    const float* __restrict__ bias,
    unsigned short* __restrict__ Qb,
    unsigned short* __restrict__ Kb,
    unsigned short* __restrict__ VTb)
{
    __shared__ alignas(16) unsigned short As[128 * 32];
    __shared__ alignas(16) unsigned short Bs[128 * 32];
    const int K = 1024;
    int t = threadIdx.x;
    int wave = t >> 6, lane = t & 63, quad = lane >> 4, l = lane & 15;
    int bm = blockIdx.x * 128, bn = blockIdx.y * 128;
    int wm = (wave >> 1) * 64, wn = (wave & 1) * 64;

    float4_t z = {0.f, 0.f, 0.f, 0.f};
    float4_t acc[4][4];
#pragma unroll
    for (int i = 0; i < 4; ++i)
#pragma unroll
        for (int j = 0; j < 4; ++j) acc[i][j] = z;

    for (int kt = 0; kt < K / 32; ++kt) {
        int k0 = kt * 32;
        if (kt) __syncthreads();
#pragma unroll
        for (int it = 0; it < 2; ++it) {
            int c = t + 256 * it;
            int row = c >> 2, col = (c & 3) * 8;
            gld_lds16(&X [(size_t)(bm + row) * K + k0 + col], &As[c * 8]);
            gld_lds16(&WT[(size_t)(bn + row) * K + k0 + col], &Bs[c * 8]);
        }
        __syncthreads();
        short8 af[4], bfr[4];
#pragma unroll
        for (int i = 0; i < 4; ++i)
            af[i] = *(const short8*)&As[(wm + i * 16 + l) * 32 + quad * 8];
#pragma unroll
        for (int j = 0; j < 4; ++j)
            bfr[j] = *(const short8*)&Bs[(wn + j * 16 + l) * 32 + quad * 8];
#pragma unroll
        for (int i = 0; i < 4; ++i)
#pragma unroll
            for (int j = 0; j < 4; ++j)
                acc[i][j] = __builtin_amdgcn_mfma_f32_16x16x32_bf16(
                    af[i], bfr[j], acc[i][j], 0, 0, 0);
    }
#pragma unroll
    for (int j = 0; j < 4; ++j) {
        int gc = bn + wn + j * 16 + l;
        float bv = bias[gc];
        int which = gc >> 10, rem = gc & 1023;
        int h = rem >> 6, d = rem & 63;
        if (which == 2) {
            int bb = bm >> 11;
            size_t rowbase = ((size_t)(bb * NH + h) * HD + d) * S_LEN;
#pragma unroll
            for (int i = 0; i < 4; ++i) {
                unsigned int u0 = __float_as_uint(acc[i][j][0] + bv) + 0x8000u;
                unsigned int u1 = __float_as_uint(acc[i][j][1] + bv) + 0x8000u;
                unsigned int u2 = __float_as_uint(acc[i][j][2] + bv) + 0x8000u;
                unsigned int u3 = __float_as_uint(acc[i][j][3] + bv) + 0x8000u;
                uint2 vv;
                vv.x = __builtin_amdgcn_perm(u1, u0, 0x07060302u);
                vv.y = __builtin_amdgcn_perm(u3, u2, 0x07060302u);
                int s0 = (bm + wm + i * 16 + quad * 4) & 2047;
                *(uint2*)&VTb[rowbase + s0] = vv;
            }
        } else {
#pragma unroll
            for (int i = 0; i < 4; ++i)
#pragma unroll
                for (int r = 0; r < 4; ++r) {
                    int gr = bm + wm + i * 16 + quad * 4 + r;
                    int b = gr >> 11, s = gr & 2047;
                    unsigned short ov = f2bf(acc[i][j][r] + bv);
                    size_t bh2 = (size_t)(b * NH + h);
                    if (which == 0) Qb[(bh2 * S_LEN + s) * HD + d] = ov;
                    else            Kb[(bh2 * S_LEN + s) * HD + d] = ov;
                }
        }
    }
}

// ---------------------------------------------------------------------------
// Flash attention (causal), barrier-free, transposed-score formulation.
//
// THIS ROUND: one 32-query chunk per wave (mirrored-pair structure removed).
// Round-1's forced register double-buffer spilled to scratch (WRITE_SIZE
// 16MB->359MB) -- reverted.  Round-0 diagnosis stands: latency-bound,
// ~7800 cy/iter vs ~600 cy compute, all pipes <20% busy, occupancy
// GRID-capped at 2 waves/SIMD.  Fix via TLP: 4096 waves (1024 blocks,
// 4 blocks/CU, 4 waves/SIMD).  K-load sharing between mirror chunks is
// sacrificed -- worthless at 3.5% HBM with L2-resident K/V.  Chunks of
// similar length grouped per block (waves balanced within a block);
// all 16 blocks of one (b,h) pinned to one XCD for L2 K/V reuse.
// Compiler's natural load-sinking schedule kept (the 159us behavior).
// ---------------------------------------------------------------------------
__global__ __launch_bounds__(256, 4) void flash_attn(
    const unsigned short* __restrict__ Qb,
    const unsigned short* __restrict__ Kb,
    const unsigned short* __restrict__ VTb,
    unsigned short* __restrict__ AO)
{
    __shared__ alignas(16) unsigned short stg[4][16 * 68];  // per-wave O staging

    int t = threadIdx.x, wave = t >> 6, lane = t & 63, quad = lane >> 4, cl = lane & 15;
    int blk = blockIdx.x;                 // 0..1023
    int bh = (blk & 7) + 8 * ((blk >> 3) & 7);   // XCD-pinned heads
    int ci = (blk >> 6) * 4 + wave;       // 0..63 chunk index (block-local balance)
    int b = bh >> 4, h = bh & 15;
    int qb = 32 * ci;
    int nkt = ((qb + 31) >> 6) + 1;

    const unsigned short* Qbase = Qb  + (size_t)bh * S_LEN * HD;
    const unsigned short* Kbase = Kb  + (size_t)bh * S_LEN * HD;
    const unsigned short* Vbase = VTb + (size_t)bh * HD * S_LEN;

    float4_t z = {0.f, 0.f, 0.f, 0.f};
    short8 bQ[2][2];
#pragma unroll
    for (int qt = 0; qt < 2; ++qt)
#pragma unroll
        for (int hh = 0; hh < 2; ++hh)
            bQ[qt][hh] = *(const short8*)&Qbase[(size_t)(qb + qt * 16 + cl) * HD + hh * 32 + quad * 8];

    float4_t acc[2][4];
#pragma unroll
    for (int qt = 0; qt < 2; ++qt)
#pragma unroll
        for (int nb = 0; nb < 4; ++nb) acc[qt][nb] = z;
    float ps[2] = {0.f, 0.f};

    for (int kt = 0; kt < nkt; ++kt) {
        int key0 = kt << 6;
        // K A-fragments: A[m=key][k=d]  (16B/lane, contiguous)
        short8 aK0[4], aK1[4];
#pragma unroll
        for (int t4 = 0; t4 < 4; ++t4) {
            const unsigned short* kr = &Kbase[(size_t)(key0 + t4 * 16 + cl) * HD + quad * 8];
            aK0[t4] = *(const short8*)kr;
            aK1[t4] = *(const short8*)(kr + 32);
        }
        // V B-fragments: slots j<4 = keys quad*4..+3, j>=4 = +16 (8B pieces)
        uint2 bvlo[2][4], bvhi[2][4];
#pragma unroll
        for (int p = 0; p < 2; ++p)
#pragma unroll
            for (int nb = 0; nb < 4; ++nb) {
                const unsigned short* vr = &Vbase[(size_t)(nb * 16 + cl) * S_LEN + key0 + p * 32 + quad * 4];
                bvlo[p][nb] = *(const uint2*)vr;
                bvhi[p][nb] = *(const uint2*)(vr + 16);
            }

        bool diag = (kt == nkt - 1);
#pragma unroll
        for (int qt = 0; qt < 2; ++qt) {
            unsigned int pk[4][2];
#pragma unroll
            for (int t4 = 0; t4 < 4; ++t4) {
                float4_t st = __builtin_amdgcn_mfma_f32_16x16x32_bf16(
                    aK1[t4], bQ[qt][1],
                    __builtin_amdgcn_mfma_f32_16x16x32_bf16(aK0[t4], bQ[qt][0], z, 0, 0, 0),
                    0, 0, 0);
                unsigned int u[4];
#pragma unroll
                for (int r = 0; r < 4; ++r) {
                    float e = __expf(st[r] * 0.125f);      // 1/sqrt(64)
                    if (diag) {
                        int key = key0 + t4 * 16 + quad * 4 + r;
                        e = (key <= qb + qt * 16 + cl) ? e : 0.f;
                    }
                    ps[qt] += e;
                    u[r] = __float_as_uint(e) + 0x8000u;    // round-to-bf16 bias
                }
                pk[t4][0] = __builtin_amdgcn_perm(u[1], u[0], 0x07060302u);
                pk[t4][1] = __builtin_amdgcn_perm(u[3], u[2], 0x07060302u);
            }
#pragma unroll
            for (int p = 0; p < 2; ++p) {
                U8 a; a.i = (int4_t){(int)pk[2 * p][0], (int)pk[2 * p][1],
                                     (int)pk[2 * p + 1][0], (int)pk[2 * p + 1][1]};
#pragma unroll
                for (int nb = 0; nb < 4; ++nb) {
                    U8 bb; bb.i = (int4_t){(int)bvlo[p][nb].x, (int)bvlo[p][nb].y,
                                           (int)bvhi[p][nb].x, (int)bvhi[p][nb].y};
                    acc[qt][nb] = __builtin_amdgcn_mfma_f32_16x16x32_bf16(
                        a.s, bb.s, acc[qt][nb], 0, 0, 0);
                }
            }
        }
    }

    // epilogue: normalize + coalesced store via per-wave LDS staging
#pragma unroll
    for (int qt = 0; qt < 2; ++qt) {
        float s = ps[qt];
        s += __shfl_xor(s, 16);
        s += __shfl_xor(s, 32);
        float inv = 1.f / s;                 // full sum for query qb+qt*16+cl
        float fr[4];
#pragma unroll
        for (int r = 0; r < 4; ++r) fr[r] = __shfl(inv, quad * 4 + r);
#pragma unroll
        for (int nb = 0; nb < 4; ++nb)
#pragma unroll
            for (int r = 0; r < 4; ++r) {
                unsigned int u = __float_as_uint(acc[qt][nb][r] * fr[r]) + 0x8000u;
                stg[wave][(quad * 4 + r) * 68 + nb * 16 + cl] = (unsigned short)(u >> 16);
            }
#pragma unroll
        for (int pass = 0; pass < 4; ++pass) {
            int idx = pass * 64 + lane;
            int row = idx >> 4, part = idx & 15;
            ushort4 v = *(const ushort4*)&stg[wave][row * 68 + part * 4];
            *(ushort4*)&AO[((size_t)b * S_LEN + qb + qt * 16 + row) * EMB + h * HD + part * 4] = v;
        }
    }
}

// ---------------------------------------------------------------------------
// GEMM2: out_f32 = AO[8192,1024]bf16 @ WoutT[1024,1024]^T + bout(f32)
// ---------------------------------------------------------------------------
__global__ __launch_bounds__(256) void gemm_out(
    const unsigned short* __restrict__ A,
    const unsigned short* __restrict__ WT,
    const float* __restrict__ bias,
    float* __restrict__ out)
{
    __shared__ alignas(16) unsigned short As[128 * 32];
    __shared__ alignas(16) unsigned short Bs[128 * 32];
    const int K = 1024;
    int t = threadIdx.x;
    int wave = t >> 6, lane = t & 63, quad = lane >> 4, l = lane & 15;
    int bm = blockIdx.x * 128, bn = blockIdx.y * 128;
    int wm = (wave >> 1) * 64, wn = (wave & 1) * 64;

    float4_t z = {0.f, 0.f, 0.f, 0.f};
    float4_t acc[4][4];
#pragma unroll
    for (int i = 0; i < 4; ++i)
#pragma unroll
        for (int j = 0; j < 4; ++j) acc[i][j] = z;

    for (int kt = 0; kt < K / 32; ++kt) {
        int k0 = kt * 32;
        if (kt) __syncthreads();
#pragma unroll
        for (int it = 0; it < 2; ++it) {
            int c = t + 256 * it;
            int row = c >> 2, col = (c & 3) * 8;
            gld_lds16(&A [(size_t)(bm + row) * K + k0 + col], &As[c * 8]);
            gld_lds16(&WT[(size_t)(bn + row) * K + k0 + col], &Bs[c * 8]);
        }
        __syncthreads();
        short8 af[4], bfr[4];
#pragma unroll
        for (int i = 0; i < 4; ++i)
            af[i] = *(const short8*)&As[(wm + i * 16 + l) * 32 + quad * 8];
#pragma unroll
        for (int j = 0; j < 4; ++j)
            bfr[j] = *(const short8*)&Bs[(wn + j * 16 + l) * 32 + quad * 8];
#pragma unroll
        for (int i = 0; i < 4; ++i)
#pragma unroll
            for (int j = 0; j < 4; ++j)
                acc[i][j] = __builtin_amdgcn_mfma_f32_16x16x32_bf16(
                    af[i], bfr[j], acc[i][j], 0, 0, 0);
    }
#pragma unroll
    for (int j = 0; j < 4; ++j) {
        int gc = bn + wn + j * 16 + l;
        float bv = bias[gc];
#pragma unroll
        for (int i = 0; i < 4; ++i) {
#pragma unroll
            for (int r = 0; r < 4; ++r) {
                int gr = bm + wm + i * 16 + quad * 4 + r;
                out[(size_t)gr * EMB + gc] = acc[i][j][r] + bv;
            }
        }
    }
}

// ---------------------------------------------------------------------------
extern "C" void kernel_launch(void* const* d_in, const int* in_sizes, int n_in,
                              void* d_out, int out_size, void* d_ws, size_t ws_size,
                              hipStream_t stream) {
    const float* x    = (const float*)d_in[0];
    // d_in[1] = causal mask (int32 tril) -- implemented analytically, not read
    const float* Wqkv = (const float*)d_in[2];
    const float* bqkv = (const float*)d_in[3];
    const float* Wout = (const float*)d_in[4];
    const float* bout = (const float*)d_in[5];
    float* out = (float*)d_out;

    // workspace (bf16): Q 16MB | K 16MB | VT 16MB | Xb/AO 16MB (aliased) |
    // WqkvT 6MB | WoutT 2MB = 72MB
    char* ws = (char*)d_ws;
    const size_t SZ = (size_t)NB * NH * S_LEN * HD * 2;  // 16 MiB
    unsigned short* Qb    = (unsigned short*)(ws);
    unsigned short* Kb    = (unsigned short*)(ws + SZ);
    unsigned short* VTb   = (unsigned short*)(ws + 2 * SZ);
    unsigned short* Xb    = (unsigned short*)(ws + 3 * SZ);
    unsigned short* AO    = (unsigned short*)(ws + 3 * SZ);  // alias with Xb
    unsigned short* WqkvT = (unsigned short*)(ws + 4 * SZ);
    unsigned short* WoutT = (unsigned short*)(ws + 4 * SZ + (size_t)3 * EMB * EMB * 2);

    int n2 = MROWS * EMB / 2;
    cvt_f32_bf16<<<dim3((n2 + 255) / 256), 256, 0, stream>>>(x, Xb, n2);
    dim3 tb(32, 8);
    transpose_f32_bf16<<<dim3(3 * EMB / 32, EMB / 32), tb, 0, stream>>>(Wqkv, WqkvT, EMB, 3 * EMB);
    transpose_f32_bf16<<<dim3(EMB / 32, EMB / 32), tb, 0, stream>>>(Wout, WoutT, EMB, EMB);
    gemm_qkv<<<dim3(MROWS / 128, 3 * EMB / 128), 256, 0, stream>>>(Xb, WqkvT, bqkv, Qb, Kb, VTb);
    flash_attn<<<dim3(1024), 256, 0, stream>>>(Qb, Kb, VTb, AO);
    gemm_out<<<dim3(MROWS / 128, EMB / 128), 256, 0, stream>>>(AO, WoutT, bout, out);
}

// Round 3
// 289.275 us; speedup vs baseline: 1.5604x; 1.4216x over previous
//
#include <hip/hip_runtime.h>

// Problem constants
#define S_LEN 2048
#define NH    16
#define HD    64
#define EMB   1024
#define NB    4
#define MROWS (NB * S_LEN)   // 8192

typedef __attribute__((ext_vector_type(8))) short  short8;   // 8 x bf16 bits (4 VGPRs)
typedef __attribute__((ext_vector_type(4))) float  float4_t; // MFMA C/D frag
typedef __attribute__((ext_vector_type(4))) int    int4_t;   // 16B int vector
union U8 { int4_t i; short8 s; };

__device__ __forceinline__ unsigned short f2bf(float f) {
    unsigned int x = __float_as_uint(f);
    unsigned int r = (x + 0x7fffu + ((x >> 16) & 1u)) >> 16;   // RNE
    return (unsigned short)r;
}

typedef const __attribute__((address_space(1))) unsigned int* gas_ptr;
typedef __attribute__((address_space(3))) unsigned int*       las_ptr;
__device__ __forceinline__ void gld_lds16(const void* g, void* l) {
    __builtin_amdgcn_global_load_lds((gas_ptr)g, (las_ptr)l, 16, 0, 0);
}

// ---------------------------------------------------------------------------
// elementwise fp32 -> bf16 (x), 2 elems/thread
// ---------------------------------------------------------------------------
__global__ void cvt_f32_bf16(const float* __restrict__ in,
                             unsigned short* __restrict__ out, int n2) {
    int i = blockIdx.x * blockDim.x + threadIdx.x;
    if (i < n2) {
        float2 v = ((const float2*)in)[i];
        ushort2 o; o.x = f2bf(v.x); o.y = f2bf(v.y);
        ((ushort2*)out)[i] = o;
    }
}

// ---------------------------------------------------------------------------
// fp32 transpose + convert: out_bf16[C][R] = in_f32[R][C]
// ---------------------------------------------------------------------------
__global__ void transpose_f32_bf16(const float* __restrict__ in,
                                   unsigned short* __restrict__ out, int R, int C) {
    __shared__ float tile[32][33];
    int n0 = blockIdx.x * 32, r0 = blockIdx.y * 32;
    int tx = threadIdx.x, ty = threadIdx.y;     // (32,8)
#pragma unroll
    for (int i = 0; i < 4; ++i)
        tile[ty + i * 8][tx] = in[(size_t)(r0 + ty + i * 8) * C + n0 + tx];
    __syncthreads();
#pragma unroll
    for (int i = 0; i < 4; ++i)
        out[(size_t)(n0 + ty + i * 8) * R + r0 + tx] = f2bf(tile[tx][ty + i * 8]);
}

// ---------------------------------------------------------------------------
// GEMM1: qkv = Xb[8192,1024] @ WqkvT[3072,1024]^T + bqkv(f32)
// epilogue scatters to Q[B,H,S,D], K[B,H,S,D], VT[B,H,D,S]  (all bf16)
// ---------------------------------------------------------------------------
__global__ __launch_bounds__(256) void gemm_qkv(
    const unsigned short* __restrict__ X,
    const unsigned short* __restrict__ WT,
    const float* __restrict__ bias,
    unsigned short* __restrict__ Qb,
    unsigned short* __restrict__ Kb,
    unsigned short* __restrict__ VTb)
{
    __shared__ alignas(16) unsigned short As[128 * 32];
    __shared__ alignas(16) unsigned short Bs[128 * 32];
    const int K = 1024;
    int t = threadIdx.x;
    int wave = t >> 6, lane = t & 63, quad = lane >> 4, l = lane & 15;
    int bm = blockIdx.x * 128, bn = blockIdx.y * 128;
    int wm = (wave >> 1) * 64, wn = (wave & 1) * 64;

    float4_t z = {0.f, 0.f, 0.f, 0.f};
    float4_t acc[4][4];
#pragma unroll
    for (int i = 0; i < 4; ++i)
#pragma unroll
        for (int j = 0; j < 4; ++j) acc[i][j] = z;

    for (int kt = 0; kt < K / 32; ++kt) {
        int k0 = kt * 32;
        if (kt) __syncthreads();
#pragma unroll
        for (int it = 0; it < 2; ++it) {
            int c = t + 256 * it;
            int row = c >> 2, col = (c & 3) * 8;
            gld_lds16(&X [(size_t)(bm + row) * K + k0 + col], &As[c * 8]);
            gld_lds16(&WT[(size_t)(bn + row) * K + k0 + col], &Bs[c * 8]);
        }
        __syncthreads();
        short8 af[4], bfr[4];
#pragma unroll
        for (int i = 0; i < 4; ++i)
            af[i] = *(const short8*)&As[(wm + i * 16 + l) * 32 + quad * 8];
#pragma unroll
        for (int j = 0; j < 4; ++j)
            bfr[j] = *(const short8*)&Bs[(wn + j * 16 + l) * 32 + quad * 8];
#pragma unroll
        for (int i = 0; i < 4; ++i)
#pragma unroll
            for (int j = 0; j < 4; ++j)
                acc[i][j] = __builtin_amdgcn_mfma_f32_16x16x32_bf16(
                    af[i], bfr[j], acc[i][j], 0, 0, 0);
    }
#pragma unroll
    for (int j = 0; j < 4; ++j) {
        int gc = bn + wn + j * 16 + l;
        float bv = bias[gc];
        int which = gc >> 10, rem = gc & 1023;
        int h = rem >> 6, d = rem & 63;
        if (which == 2) {
            int bb = bm >> 11;
            size_t rowbase = ((size_t)(bb * NH + h) * HD + d) * S_LEN;
#pragma unroll
            for (int i = 0; i < 4; ++i) {
                unsigned int u0 = __float_as_uint(acc[i][j][0] + bv) + 0x8000u;
                unsigned int u1 = __float_as_uint(acc[i][j][1] + bv) + 0x8000u;
                unsigned int u2 = __float_as_uint(acc[i][j][2] + bv) + 0x8000u;
                unsigned int u3 = __float_as_uint(acc[i][j][3] + bv) + 0x8000u;
                uint2 vv;
                vv.x = __builtin_amdgcn_perm(u1, u0, 0x07060302u);
                vv.y = __builtin_amdgcn_perm(u3, u2, 0x07060302u);
                int s0 = (bm + wm + i * 16 + quad * 4) & 2047;
                *(uint2*)&VTb[rowbase + s0] = vv;
            }
        } else {
#pragma unroll
            for (int i = 0; i < 4; ++i)
#pragma unroll
                for (int r = 0; r < 4; ++r) {
                    int gr = bm + wm + i * 16 + quad * 4 + r;
                    int b = gr >> 11, s = gr & 2047;
                    unsigned short ov = f2bf(acc[i][j][r] + bv);
                    size_t bh2 = (size_t)(b * NH + h);
                    if (which == 0) Qb[(bh2 * S_LEN + s) * HD + d] = ov;
                    else            Kb[(bh2 * S_LEN + s) * HD + d] = ov;
                }
        }
    }
}

// ---------------------------------------------------------------------------
// Flash attention (causal), LDS-staged K/V shared across the block.
//
// THIS ROUND: rounds 0-2 proved the compiler will not hold a prefetched
// K/V tile in registers (R1: spilled to scratch; R0/R2: sank loads to
// uses, serializing ~24 x 300cy latencies/iter).  Switch to the m97 GEMM
// staging structure: per block, all 256 threads stage the 64-key K-tile
// (8KB) + V-tile (8KB) into LDS via global_load_lds, 2 barriers/tile;
// latency hidden by co-resident blocks (LDS 16.4KB -> 4+ blocks/CU).
// The block's 4 waves share one (b,h) and consecutive 32-query chunks,
// so one staged tile feeds all 4 waves: 4x fewer global loads than R2.
// LDS bank conflicts on the stride-128B row reads are killed by an XOR
// swizzle (byte ^= (row&7)<<4) applied on the GLOBAL source address at
// stage time (gld_lds writes linearly; rule: swizzle both sides or
// neither).  Verified: b128 K-reads and b64 V-reads land min-cycle.
// ---------------------------------------------------------------------------
__global__ __launch_bounds__(256) void flash_attn(
    const unsigned short* __restrict__ Qb,
    const unsigned short* __restrict__ Kb,
    const unsigned short* __restrict__ VTb,
    unsigned short* __restrict__ AO)
{
    // Kbuf [64 keys][64 d] swizzled (8KB) | Vbuf [64 d][64 keys] swizzled (8KB)
    // epilogue: first 8704B reused as per-wave O staging
    __shared__ alignas(16) unsigned short smem[8192];
    unsigned short* Kbuf = smem;
    unsigned short* Vbuf = smem + 4096;

    int t = threadIdx.x, wave = t >> 6, lane = t & 63, quad = lane >> 4, cl = lane & 15;
    int blk = blockIdx.x;                        // 0..1023
    int bh = (blk & 7) + 8 * ((blk >> 3) & 7);   // XCD-pinned heads
    int g4 = blk >> 6;                           // 0..15 chunk group
    int ci = g4 * 4 + wave;                      // 0..63 chunk index
    int b = bh >> 4, h = bh & 15;
    int qb = 32 * ci;
    int nkt = ((qb + 31) >> 6) + 1;              // tiles this wave needs
    int nkt_max = ((32 * (g4 * 4 + 3) + 31) >> 6) + 1;  // uniform per block

    const unsigned short* Qbase = Qb  + (size_t)bh * S_LEN * HD;
    const unsigned short* Kbase = Kb  + (size_t)bh * S_LEN * HD;
    const unsigned short* Vbase = VTb + (size_t)bh * HD * S_LEN;

    float4_t z = {0.f, 0.f, 0.f, 0.f};
    short8 bQ[2][2];
#pragma unroll
    for (int qt = 0; qt < 2; ++qt)
#pragma unroll
        for (int hh = 0; hh < 2; ++hh)
            bQ[qt][hh] = *(const short8*)&Qbase[(size_t)(qb + qt * 16 + cl) * HD + hh * 32 + quad * 8];

    float4_t acc[2][4];
#pragma unroll
    for (int qt = 0; qt < 2; ++qt)
#pragma unroll
        for (int nb = 0; nb < 4; ++nb) acc[qt][nb] = z;
    float ps[2] = {0.f, 0.f};

    // kt-invariant swizzled LDS read offsets (bytes)
    const char* Kc = (const char*)Kbuf;
    const char* Vc = (const char*)Vbuf;
    int koff0[4], koff1[4];
#pragma unroll
    for (int t4 = 0; t4 < 4; ++t4) {
        int row = t4 * 16 + cl, sw = row & 7;
        koff0[t4] = (row << 7) | ((quad ^ sw) << 4);
        koff1[t4] = (row << 7) | (((quad + 4) ^ sw) << 4);
    }
    int voff[2][4][2];
#pragma unroll
    for (int p = 0; p < 2; ++p)
#pragma unroll
        for (int nb = 0; nb < 4; ++nb) {
            int row = nb * 16 + cl, sw = row & 7;
            int bo = p * 64 + quad * 8, bo2 = bo + 32;
            voff[p][nb][0] = (row << 7) | (((bo >> 4) ^ sw) << 4) | (bo & 15);
            voff[p][nb][1] = (row << 7) | (((bo2 >> 4) ^ sw) << 4) | (bo2 & 15);
        }

    for (int kt = 0; kt < nkt_max; ++kt) {
        int key0 = kt << 6;
        if (kt) __syncthreads();                 // prev compute done reading LDS
        // stage K+V tile, source-swizzled: LDS slot (row, j) <- global col16 j^(row&7)
#pragma unroll
        for (int i = 0; i < 2; ++i) {
            int s = t + 256 * i;
            int row = s >> 3, c16 = (s & 7) ^ (row & 7);
            gld_lds16(&Kbase[(size_t)(key0 + row) * HD + c16 * 8], &Kbuf[s * 8]);
            gld_lds16(&Vbase[(size_t)row * S_LEN + key0 + c16 * 8], &Vbuf[s * 8]);
        }
        __syncthreads();                         // drains vmcnt -> tile visible

        if (kt < nkt) {
            // K A-fragments from LDS (swizzled)
            short8 aK0[4], aK1[4];
#pragma unroll
            for (int t4 = 0; t4 < 4; ++t4) {
                aK0[t4] = *(const short8*)(Kc + koff0[t4]);
                aK1[t4] = *(const short8*)(Kc + koff1[t4]);
            }
            // V B-fragments from LDS (swizzled)
            uint2 bvlo[2][4], bvhi[2][4];
#pragma unroll
            for (int p = 0; p < 2; ++p)
#pragma unroll
                for (int nb = 0; nb < 4; ++nb) {
                    bvlo[p][nb] = *(const uint2*)(Vc + voff[p][nb][0]);
                    bvhi[p][nb] = *(const uint2*)(Vc + voff[p][nb][1]);
                }

            bool diag = (kt == nkt - 1);
#pragma unroll
            for (int qt = 0; qt < 2; ++qt) {
                unsigned int pk[4][2];
#pragma unroll
                for (int t4 = 0; t4 < 4; ++t4) {
                    float4_t st = __builtin_amdgcn_mfma_f32_16x16x32_bf16(
                        aK1[t4], bQ[qt][1],
                        __builtin_amdgcn_mfma_f32_16x16x32_bf16(aK0[t4], bQ[qt][0], z, 0, 0, 0),
                        0, 0, 0);
                    unsigned int u[4];
#pragma unroll
                    for (int r = 0; r < 4; ++r) {
                        float e = __expf(st[r] * 0.125f);      // 1/sqrt(64)
                        if (diag) {
                            int key = key0 + t4 * 16 + quad * 4 + r;
                            e = (key <= qb + qt * 16 + cl) ? e : 0.f;
                        }
                        ps[qt] += e;
                        u[r] = __float_as_uint(e) + 0x8000u;    // round-to-bf16 bias
                    }
                    pk[t4][0] = __builtin_amdgcn_perm(u[1], u[0], 0x07060302u);
                    pk[t4][1] = __builtin_amdgcn_perm(u[3], u[2], 0x07060302u);
                }
#pragma unroll
                for (int p = 0; p < 2; ++p) {
                    U8 a; a.i = (int4_t){(int)pk[2 * p][0], (int)pk[2 * p][1],
                                         (int)pk[2 * p + 1][0], (int)pk[2 * p + 1][1]};
#pragma unroll
                    for (int nb = 0; nb < 4; ++nb) {
                        U8 bb; bb.i = (int4_t){(int)bvlo[p][nb].x, (int)bvlo[p][nb].y,
                                               (int)bvhi[p][nb].x, (int)bvhi[p][nb].y};
                        acc[qt][nb] = __builtin_amdgcn_mfma_f32_16x16x32_bf16(
                            a.s, bb.s, acc[qt][nb], 0, 0, 0);
                    }
                }
            }
        }
    }

    __syncthreads();   // all waves done with K/V LDS before stg reuse
    unsigned short* stgw = smem + wave * (16 * 68);

    // epilogue: normalize + coalesced store via per-wave LDS staging
#pragma unroll
    for (int qt = 0; qt < 2; ++qt) {
        float s = ps[qt];
        s += __shfl_xor(s, 16);
        s += __shfl_xor(s, 32);
        float inv = 1.f / s;                 // full sum for query qb+qt*16+cl
        float fr[4];
#pragma unroll
        for (int r = 0; r < 4; ++r) fr[r] = __shfl(inv, quad * 4 + r);
#pragma unroll
        for (int nb = 0; nb < 4; ++nb)
#pragma unroll
            for (int r = 0; r < 4; ++r) {
                unsigned int u = __float_as_uint(acc[qt][nb][r] * fr[r]) + 0x8000u;
                stgw[(quad * 4 + r) * 68 + nb * 16 + cl] = (unsigned short)(u >> 16);
            }
#pragma unroll
        for (int pass = 0; pass < 4; ++pass) {
            int idx = pass * 64 + lane;
            int row = idx >> 4, part = idx & 15;
            ushort4 v = *(const ushort4*)&stgw[row * 68 + part * 4];
            *(ushort4*)&AO[((size_t)b * S_LEN + qb + qt * 16 + row) * EMB + h * HD + part * 4] = v;
        }
    }
}

// ---------------------------------------------------------------------------
// GEMM2: out_f32 = AO[8192,1024]bf16 @ WoutT[1024,1024]^T + bout(f32)
// ---------------------------------------------------------------------------
__global__ __launch_bounds__(256) void gemm_out(
    const unsigned short* __restrict__ A,
    const unsigned short* __restrict__ WT,
    const float* __restrict__ bias,
    float* __restrict__ out)
{
    __shared__ alignas(16) unsigned short As[128 * 32];
    __shared__ alignas(16) unsigned short Bs[128 * 32];
    const int K = 1024;
    int t = threadIdx.x;
    int wave = t >> 6, lane = t & 63, quad = lane >> 4, l = lane & 15;
    int bm = blockIdx.x * 128, bn = blockIdx.y * 128;
    int wm = (wave >> 1) * 64, wn = (wave & 1) * 64;

    float4_t z = {0.f, 0.f, 0.f, 0.f};
    float4_t acc[4][4];
#pragma unroll
    for (int i = 0; i < 4; ++i)
#pragma unroll
        for (int j = 0; j < 4; ++j) acc[i][j] = z;

    for (int kt = 0; kt < K / 32; ++kt) {
        int k0 = kt * 32;
        if (kt) __syncthreads();
#pragma unroll
        for (int it = 0; it < 2; ++it) {
            int c = t + 256 * it;
            int row = c >> 2, col = (c & 3) * 8;
            gld_lds16(&A [(size_t)(bm + row) * K + k0 + col], &As[c * 8]);
            gld_lds16(&WT[(size_t)(bn + row) * K + k0 + col], &Bs[c * 8]);
        }
        __syncthreads();
        short8 af[4], bfr[4];
#pragma unroll
        for (int i = 0; i < 4; ++i)
            af[i] = *(const short8*)&As[(wm + i * 16 + l) * 32 + quad * 8];
#pragma unroll
        for (int j = 0; j < 4; ++j)
            bfr[j] = *(const short8*)&Bs[(wn + j * 16 + l) * 32 + quad * 8];
#pragma unroll
        for (int i = 0; i < 4; ++i)
#pragma unroll
            for (int j = 0; j < 4; ++j)
                acc[i][j] = __builtin_amdgcn_mfma_f32_16x16x32_bf16(
                    af[i], bfr[j], acc[i][j], 0, 0, 0);
    }
#pragma unroll
    for (int j = 0; j < 4; ++j) {
        int gc = bn + wn + j * 16 + l;
        float bv = bias[gc];
#pragma unroll
        for (int i = 0; i < 4; ++i) {
#pragma unroll
            for (int r = 0; r < 4; ++r) {
                int gr = bm + wm + i * 16 + quad * 4 + r;
                out[(size_t)gr * EMB + gc] = acc[i][j][r] + bv;
            }
        }
    }
}

// ---------------------------------------------------------------------------
extern "C" void kernel_launch(void* const* d_in, const int* in_sizes, int n_in,
                              void* d_out, int out_size, void* d_ws, size_t ws_size,
                              hipStream_t stream) {
    const float* x    = (const float*)d_in[0];
    // d_in[1] = causal mask (int32 tril) -- implemented analytically, not read
    const float* Wqkv = (const float*)d_in[2];
    const float* bqkv = (const float*)d_in[3];
    const float* Wout = (const float*)d_in[4];
    const float* bout = (const float*)d_in[5];
    float* out = (float*)d_out;

    // workspace (bf16): Q 16MB | K 16MB | VT 16MB | Xb/AO 16MB (aliased) |
    // WqkvT 6MB | WoutT 2MB = 72MB
    char* ws = (char*)d_ws;
    const size_t SZ = (size_t)NB * NH * S_LEN * HD * 2;  // 16 MiB
    unsigned short* Qb    = (unsigned short*)(ws);
    unsigned short* Kb    = (unsigned short*)(ws + SZ);
    unsigned short* VTb   = (unsigned short*)(ws + 2 * SZ);
    unsigned short* Xb    = (unsigned short*)(ws + 3 * SZ);
    unsigned short* AO    = (unsigned short*)(ws + 3 * SZ);  // alias with Xb
    unsigned short* WqkvT = (unsigned short*)(ws + 4 * SZ);
    unsigned short* WoutT = (unsigned short*)(ws + 4 * SZ + (size_t)3 * EMB * EMB * 2);

    int n2 = MROWS * EMB / 2;
    cvt_f32_bf16<<<dim3((n2 + 255) / 256), 256, 0, stream>>>(x, Xb, n2);
    dim3 tb(32, 8);
    transpose_f32_bf16<<<dim3(3 * EMB / 32, EMB / 32), tb, 0, stream>>>(Wqkv, WqkvT, EMB, 3 * EMB);
    transpose_f32_bf16<<<dim3(EMB / 32, EMB / 32), tb, 0, stream>>>(Wout, WoutT, EMB, EMB);
    gemm_qkv<<<dim3(MROWS / 128, 3 * EMB / 128), 256, 0, stream>>>(Xb, WqkvT, bqkv, Qb, Kb, VTb);
    flash_attn<<<dim3(1024), 256, 0, stream>>>(Qb, Kb, VTb, AO);
    gemm_out<<<dim3(MROWS / 128, EMB / 128), 256, 0, stream>>>(AO, WoutT, bout, out);
}